// Round 8
// baseline (38.703 us; speedup 1.0000x reference)
//
#include <hip/hip_runtime.h>
#include <hip/hip_bf16.h>
#include <math.h>

// QuadraticNetCholesky fused kernel, round 8.
// y = x^T (L L^T) x = ||L^T x||^2 ; v_j = sum_{i>=j} x_i * c[i(i+1)/2 + j].
// R8: vectorize stage-3 LDS both ways.
//  - produce: mfma(W3,h2) -> D[row=t][col=sample]; lane holds 4 consecutive t
//    for one sample -> ONE ds_write_b128 into c_buf[sample][t] (was 4 b32).
//  - consume: halves split by t-range (not j-parity); each thread reads its
//    16 t as 4x ds_read_b128 and runs a constexpr-unrolled t->(i,j) fma loop
//    (v[24] static-indexed, stays in registers). Partial v exchanged at end.

constexpr int NI  = 24;
constexpr int H1  = 128;
constexpr int H2  = 32;
constexpr int SPB = 128;     // samples per block (256 threads, 4 waves)
constexpr int NT_TOT = 19;   // ceil(300/16) W3 row tiles
constexpr int W3R = 304;
constexpr float LOG2E = 1.4426950408889634f;
constexpr float LN2SQ = 0.4804530139182014f;   // ln(2)^2

typedef __attribute__((ext_vector_type(8))) short bf16x8;
typedef __attribute__((ext_vector_type(4))) float f32x4;

struct TriMap { unsigned char i[320]; unsigned char j[320]; };
constexpr TriMap mk_map() {
    TriMap m{};
    int t = 0;
    for (int i = 0; i < NI; ++i)
        for (int j = 0; j <= i; ++j) { m.i[t] = (unsigned char)i; m.j[t] = (unsigned char)j; ++t; }
    for (; t < 320; ++t) { m.i[t] = 0; m.j[t] = 0; }
    return m;
}
constexpr TriMap TM = mk_map();

__device__ __forceinline__ float elu_f(float v) {
    return v > 0.0f ? v : __expf(v) - 1.0f;
}
__device__ __forceinline__ float exp2_hw(float x) {
    float r; asm("v_exp_f32 %0, %1" : "=v"(r) : "v"(x)); return r;
}
__device__ __forceinline__ float log2_hw(float x) {
    float r; asm("v_log_f32 %0, %1" : "=v"(r) : "v"(x)); return r;
}
// softplus(z)/ln2 with z' = z*log2e as input: max(z',0) + log2(1+2^-|z'|)
__device__ __forceinline__ float softplus_g(float zp) {
    return fmaxf(zp, 0.0f) + log2_hw(1.0f + exp2_hw(-fabsf(zp)));
}
__device__ __forceinline__ unsigned short f2bf(float f) {
    return __builtin_bit_cast(unsigned short, __float2bfloat16(f));
}
__device__ __forceinline__ unsigned int pk2(float a, float b) {
    return (unsigned int)f2bf(a) | ((unsigned int)f2bf(b) << 16);
}

// ---- prologue: bf16 weight tables in d_ws ----
// shorts: w1b [128][32] @0 (K-pad 24->32 zeros); w2b [32][128] @4096;
//         w3b [304][32] @8192 (pre-scaled by log2e); b3s f32[304] @short 17920.
__global__ void wcvt(const float* __restrict__ W1, const float* __restrict__ W2,
                     const float* __restrict__ W3, const float* __restrict__ b3,
                     unsigned short* __restrict__ ws) {
    int idx = blockIdx.x * 256 + threadIdx.x;
    if (idx < 4096) {
        int n = idx >> 5, k = idx & 31;
        ws[idx] = f2bf(k < NI ? W1[n * NI + k] : 0.0f);
    } else if (idx < 8192) {
        ws[idx] = f2bf(W2[idx - 4096]);
    } else if (idx < 8192 + W3R * H2) {
        int j = idx - 8192;
        int t = j >> 5;
        ws[idx] = f2bf(t < 300 ? W3[j] * LOG2E : 0.0f);
    } else if (idx < 8192 + W3R * H2 + W3R) {
        int t = idx - (8192 + W3R * H2);
        float* b3s = reinterpret_cast<float*>(ws + 17920);
        b3s[t] = (t < 300) ? b3[t] * LOG2E : 0.0f;
    }
}

// consume 16 t-values [T0, T0+16) from own c_buf row; fully static indices.
template<int CH, int HF>
__device__ __forceinline__ void consume3(const float* __restrict__ crow,
                                         const float xr[NI], float v[NI]) {
    constexpr int T0 = CH * 32 + HF * 16;
    if constexpr (T0 < 300) {
        const f32x4* p = reinterpret_cast<const f32x4*>(crow + HF * 16);
        f32x4 cc[4];
        cc[0] = p[0]; cc[1] = p[1]; cc[2] = p[2]; cc[3] = p[3];
        #pragma unroll
        for (int tl = 0; tl < 16; ++tl) {
            if (T0 + tl < 300)
                v[TM.j[T0 + tl]] =
                    fmaf(xr[TM.i[T0 + tl]], cc[tl >> 2][tl & 3], v[TM.j[T0 + tl]]);
        }
    }
}

template<int CH>
__device__ __forceinline__ void chunk3(
    int w_hi, int w_lo, int lr, int lq, int sid, int half,
    const unsigned short* __restrict__ w3b, const float* __restrict__ b3s,
    const float xr[NI], float v[NI],
    float* __restrict__ c_buf, const unsigned short* __restrict__ h2b)
{
    const int my_nt = 2 * CH + w_hi;          // wave-uniform N-tile
    if (my_nt < NT_TOT) {
        const int trow = my_nt * 16;
        // A-frag: row(lane&15)=t-in-tile, k=8lq+j
        bf16x8 af = *reinterpret_cast<const bf16x8*>(w3b + (trow + lr) * H2 + lq * 8);
        const float4 b4 = *reinterpret_cast<const float4*>(b3s + trow + 4 * lq);
        #pragma unroll
        for (int q = 0; q < 4; ++q) {
            const int st = 4 * w_lo + q;
            bf16x8 hb = *reinterpret_cast<const bf16x8*>(h2b + (st * 16 + lr) * 40 + lq * 8);
            f32x4 a = {0.f, 0.f, 0.f, 0.f};
            a = __builtin_amdgcn_mfma_f32_16x16x32_bf16(af, hb, a, 0, 0, 0);
            // D: row(4lq+r)=t-in-tile, col(lane&15)=sample-in-st-tile
            f32x4 w;
            w[0] = softplus_g(a[0] + b4.x);
            w[1] = softplus_g(a[1] + b4.y);
            w[2] = softplus_g(a[2] + b4.z);
            w[3] = softplus_g(a[3] + b4.w);
            *reinterpret_cast<f32x4*>(
                c_buf + (st * 16 + lr) * 36 + (my_nt & 1) * 16 + 4 * lq) = w;
        }
    }
    __syncthreads();
    if (half == 0) consume3<CH, 0>(c_buf + sid * 36, xr, v);
    else           consume3<CH, 1>(c_buf + sid * 36, xr, v);
    __syncthreads();
}

__global__ __launch_bounds__(256, 4) void qnet_fused(
    const float* __restrict__ x,
    const unsigned short* __restrict__ w1b, const float* __restrict__ b1,
    const unsigned short* __restrict__ w2b, const float* __restrict__ b2,
    const unsigned short* __restrict__ w3b, const float* __restrict__ b3s,
    float* __restrict__ y, int B)
{
    // Layout (bytes): xb [128][40]sh @0..10240 ; h1s [128][40]sh @10240..20480 ;
    // h2b [128][40]sh @20480..30720. After stage 2, xb/h1s die and the region
    // becomes c_buf [128][36]f32 (18432 B); after last chunk c_buf becomes
    // vx [128][24]f32 (12288 B).
    __shared__ __align__(16) unsigned char L[30720];
    unsigned short* xb  = reinterpret_cast<unsigned short*>(L);          // [128][40]
    unsigned short* h1s = reinterpret_cast<unsigned short*>(L + 10240);  // [128][40]
    unsigned short* h2b = reinterpret_cast<unsigned short*>(L + 20480);  // [128][40]
    float* c_buf = reinterpret_cast<float*>(L);                          // [128][36] overlay

    const int tid  = threadIdx.x;
    const int sid  = tid & (SPB - 1);
    const int lane = tid & 63;
    const int lr   = lane & 15, lq = lane >> 4;
    const int half = __builtin_amdgcn_readfirstlane(tid >> 7);
    const int wid  = __builtin_amdgcn_readfirstlane(tid >> 6);
    const int w_hi = wid >> 1, w_lo = wid & 1;
    const size_t sbase = (size_t)blockIdx.x * SPB;

    // ---- x: fp32 in regs (for quadratic form) + bf16 once into xb ----
    float xr[NI];
    {
        const float4* xp4 = reinterpret_cast<const float4*>(x + (sbase + sid) * NI);
        #pragma unroll
        for (int q = 0; q < NI / 4; ++q) {
            float4 t4 = xp4[q];
            xr[4*q+0] = t4.x; xr[4*q+1] = t4.y; xr[4*q+2] = t4.z; xr[4*q+3] = t4.w;
        }
    }
    if (half == 0) {
        unsigned int pk[12];
        #pragma unroll
        for (int q = 0; q < 12; ++q) pk[q] = pk2(xr[2*q], xr[2*q+1]);
        uint4* dst = reinterpret_cast<uint4*>(xb + sid * 40);
        dst[0] = make_uint4(pk[0], pk[1], pk[2], pk[3]);
        dst[1] = make_uint4(pk[4], pk[5], pk[6], pk[7]);
        dst[2] = make_uint4(pk[8], pk[9], pk[10], pk[11]);
    } else {
        *reinterpret_cast<uint4*>(xb + sid * 40 + 24) = make_uint4(0, 0, 0, 0);  // K-pad
    }
    __syncthreads();

    // ---- stages 1+2, K-chunked by 32 h1-rows; stage-2 partials in regs ----
    f32x4 acc[2][2];
    #pragma unroll
    for (int u = 0; u < 2; ++u)
        #pragma unroll
        for (int n2 = 0; n2 < 2; ++n2) acc[u][n2] = (f32x4){0.f, 0.f, 0.f, 0.f};

    #pragma unroll
    for (int kk = 0; kk < 4; ++kk) {
        // stage 1: h1 rows [32kk, 32kk+32) for all 128 samples
        const int nt1 = 2 * kk + w_hi;
        bf16x8 af = *reinterpret_cast<const bf16x8*>(w1b + (nt1 * 16 + lr) * 32 + lq * 8);
        const float4 bb1 = *reinterpret_cast<const float4*>(b1 + nt1 * 16 + 4 * lq);
        #pragma unroll
        for (int q = 0; q < 4; ++q) {
            const int st = 4 * w_lo + q;
            bf16x8 bf = *reinterpret_cast<const bf16x8*>(xb + (st * 16 + lr) * 40 + lq * 8);
            f32x4 a = {0.f, 0.f, 0.f, 0.f};
            a = __builtin_amdgcn_mfma_f32_16x16x32_bf16(af, bf, a, 0, 0, 0);
            unsigned int p0 = pk2(elu_f(a[0] + bb1.x), elu_f(a[1] + bb1.y));
            unsigned int p1 = pk2(elu_f(a[2] + bb1.z), elu_f(a[3] + bb1.w));
            unsigned long long pw = (unsigned long long)p0 | ((unsigned long long)p1 << 32);
            // sample = st*16+lr; local col = w_hi*16 + 4lq + r
            *reinterpret_cast<unsigned long long*>(
                h1s + (st * 16 + lr) * 40 + w_hi * 16 + 4 * lq) = pw;
        }
        __syncthreads();
        // stage 2: accumulate this K-chunk into register C-tiles
        #pragma unroll
        for (int u = 0; u < 2; ++u) {
            const int st2 = 2 * wid + u;
            bf16x8 hb = *reinterpret_cast<const bf16x8*>(h1s + (st2 * 16 + lr) * 40 + lq * 8);
            #pragma unroll
            for (int n2 = 0; n2 < 2; ++n2) {
                bf16x8 wf = *reinterpret_cast<const bf16x8*>(
                    w2b + (n2 * 16 + lr) * H1 + kk * 32 + lq * 8);
                acc[u][n2] = __builtin_amdgcn_mfma_f32_16x16x32_bf16(wf, hb, acc[u][n2], 0, 0, 0);
            }
        }
        __syncthreads();
    }

    // ---- finish h2: elu + bias, pack bf16 to h2b ----
    #pragma unroll
    for (int u = 0; u < 2; ++u) {
        const int st2 = 2 * wid + u;
        #pragma unroll
        for (int n2 = 0; n2 < 2; ++n2) {
            const float4 bb2 = *reinterpret_cast<const float4*>(b2 + n2 * 16 + 4 * lq);
            unsigned int p0 = pk2(elu_f(acc[u][n2][0] + bb2.x), elu_f(acc[u][n2][1] + bb2.y));
            unsigned int p1 = pk2(elu_f(acc[u][n2][2] + bb2.z), elu_f(acc[u][n2][3] + bb2.w));
            unsigned long long pw = (unsigned long long)p0 | ((unsigned long long)p1 << 32);
            *reinterpret_cast<unsigned long long*>(
                h2b + (st2 * 16 + lr) * 40 + n2 * 16 + 4 * lq) = pw;
        }
    }
    __syncthreads();   // h2b ready; xb/h1s dead -> region becomes c_buf

    // ---- stage 3: 10 chunks of 32 tril-cols, t-range-split consumption ----
    float v[NI];
    #pragma unroll
    for (int q = 0; q < NI; ++q) v[q] = 0.f;

    chunk3<0>(w_hi, w_lo, lr, lq, sid, half, w3b, b3s, xr, v, c_buf, h2b);
    chunk3<1>(w_hi, w_lo, lr, lq, sid, half, w3b, b3s, xr, v, c_buf, h2b);
    chunk3<2>(w_hi, w_lo, lr, lq, sid, half, w3b, b3s, xr, v, c_buf, h2b);
    chunk3<3>(w_hi, w_lo, lr, lq, sid, half, w3b, b3s, xr, v, c_buf, h2b);
    chunk3<4>(w_hi, w_lo, lr, lq, sid, half, w3b, b3s, xr, v, c_buf, h2b);
    chunk3<5>(w_hi, w_lo, lr, lq, sid, half, w3b, b3s, xr, v, c_buf, h2b);
    chunk3<6>(w_hi, w_lo, lr, lq, sid, half, w3b, b3s, xr, v, c_buf, h2b);
    chunk3<7>(w_hi, w_lo, lr, lq, sid, half, w3b, b3s, xr, v, c_buf, h2b);
    chunk3<8>(w_hi, w_lo, lr, lq, sid, half, w3b, b3s, xr, v, c_buf, h2b);
    chunk3<9>(w_hi, w_lo, lr, lq, sid, half, w3b, b3s, xr, v, c_buf, h2b);

    // ---- combine partial v across halves; y = ln2^2 * sum v_j^2 ----
    float* vx = c_buf;   // c_buf dead; rows stride 24 f32 (96 B, 16-aligned)
    if (half == 1) {
        f32x4* dst = reinterpret_cast<f32x4*>(vx + sid * 24);
        #pragma unroll
        for (int q = 0; q < 6; ++q) {
            f32x4 t4 = { v[4*q], v[4*q+1], v[4*q+2], v[4*q+3] };
            dst[q] = t4;
        }
    }
    __syncthreads();
    if (half == 0) {
        const f32x4* src = reinterpret_cast<const f32x4*>(vx + sid * 24);
        float acc_y = 0.f;
        #pragma unroll
        for (int q = 0; q < 6; ++q) {
            f32x4 t4 = src[q];
            #pragma unroll
            for (int r = 0; r < 4; ++r) {
                float sv = v[4*q + r] + t4[r];
                acc_y = fmaf(sv, sv, acc_y);
            }
        }
        y[sbase + sid] = LN2SQ * acc_y;
    }
}

extern "C" void kernel_launch(void* const* d_in, const int* in_sizes, int n_in,
                              void* d_out, int out_size, void* d_ws, size_t ws_size,
                              hipStream_t stream) {
    const float* x  = (const float*)d_in[0];
    const float* W1 = (const float*)d_in[1];
    const float* b1 = (const float*)d_in[2];
    const float* W2 = (const float*)d_in[3];
    const float* b2 = (const float*)d_in[4];
    const float* W3 = (const float*)d_in[5];
    const float* b3 = (const float*)d_in[6];
    float* y = (float*)d_out;

    unsigned short* ws = (unsigned short*)d_ws;      // 37056 B used
    const unsigned short* w1b = ws;
    const unsigned short* w2b = ws + 4096;
    const unsigned short* w3b = ws + 8192;
    const float* b3s = reinterpret_cast<const float*>(ws + 17920);

    const int B = in_sizes[0] / NI;   // 131072, divisible by SPB
    const int cvt_elems = 8192 + W3R * H2 + W3R;
    wcvt<<<dim3((cvt_elems + 255) / 256), dim3(256), 0, stream>>>(W1, W2, W3, b3, ws);
    qnet_fused<<<dim3(B / SPB), dim3(256), 0, stream>>>(
        x, w1b, b1, w2b, b2, w3b, b3s, y, B);
}

// Round 9
// 37.512 us; speedup vs baseline: 1.0317x; 1.0317x over previous
//
#include <hip/hip_runtime.h>
#include <hip/hip_bf16.h>
#include <math.h>

// QuadraticNetCholesky fused kernel, round 9.
// y = x^T (L L^T) x = ||L^T x||^2 ; v_j = sum_{i>=j} x_i * c[i(i+1)/2 + j].
// R9: barrier elimination. 128-thread blocks (64 samples, 2 waves); all
// producer->consumer LDS flows are wave-private (stage1/2: wave owns its 32
// samples; stage3: wave owns c-columns 16h..16h+15 = parity of my_nt=2CH+h),
// so intra-wave in-order LDS replaces __syncthreads. 3 cheap 2-wave barriers
// remain (h2 exchange + final v exchange). LDS 14336 B -> 8 blocks/CU, grid
// 2048 = exactly 8/CU resident, 16 waves/CU.

constexpr int NI  = 24;
constexpr int H1  = 128;
constexpr int H2  = 32;
constexpr int SPB = 64;      // samples per block (128 threads, 2 waves)
constexpr int NT_TOT = 19;   // ceil(300/16) W3 row tiles
constexpr int W3R = 304;
constexpr float LOG2E = 1.4426950408889634f;
constexpr float LN2SQ = 0.4804530139182014f;   // ln(2)^2

typedef __attribute__((ext_vector_type(8))) short bf16x8;
typedef __attribute__((ext_vector_type(4))) float f32x4;

struct TriMap { unsigned char i[320]; unsigned char j[320]; };
constexpr TriMap mk_map() {
    TriMap m{};
    int t = 0;
    for (int i = 0; i < NI; ++i)
        for (int j = 0; j <= i; ++j) { m.i[t] = (unsigned char)i; m.j[t] = (unsigned char)j; ++t; }
    for (; t < 320; ++t) { m.i[t] = 0; m.j[t] = 0; }
    return m;
}
constexpr TriMap TM = mk_map();

__device__ __forceinline__ float elu_f(float v) {
    return v > 0.0f ? v : __expf(v) - 1.0f;
}
__device__ __forceinline__ float exp2_hw(float x) {
    float r; asm("v_exp_f32 %0, %1" : "=v"(r) : "v"(x)); return r;
}
__device__ __forceinline__ float log2_hw(float x) {
    float r; asm("v_log_f32 %0, %1" : "=v"(r) : "v"(x)); return r;
}
// softplus(z)/ln2 with z' = z*log2e as input: max(z',0) + log2(1+2^-|z'|)
__device__ __forceinline__ float softplus_g(float zp) {
    return fmaxf(zp, 0.0f) + log2_hw(1.0f + exp2_hw(-fabsf(zp)));
}
__device__ __forceinline__ unsigned short f2bf(float f) {
    return __builtin_bit_cast(unsigned short, __float2bfloat16(f));
}
__device__ __forceinline__ unsigned int pk2(float a, float b) {
    return (unsigned int)f2bf(a) | ((unsigned int)f2bf(b) << 16);
}

// ---- prologue: bf16 weight tables in d_ws ----
// shorts: w1b [128][32] @0 (K-pad 24->32 zeros); w2b [32][128] @4096;
//         w3b [304][32] @8192 (pre-scaled by log2e); b3s f32[304] @short 17920.
__global__ void wcvt(const float* __restrict__ W1, const float* __restrict__ W2,
                     const float* __restrict__ W3, const float* __restrict__ b3,
                     unsigned short* __restrict__ ws) {
    int idx = blockIdx.x * 256 + threadIdx.x;
    if (idx < 4096) {
        int n = idx >> 5, k = idx & 31;
        ws[idx] = f2bf(k < NI ? W1[n * NI + k] : 0.0f);
    } else if (idx < 8192) {
        ws[idx] = f2bf(W2[idx - 4096]);
    } else if (idx < 8192 + W3R * H2) {
        int j = idx - 8192;
        int t = j >> 5;
        ws[idx] = f2bf(t < 300 ? W3[j] * LOG2E : 0.0f);
    } else if (idx < 8192 + W3R * H2 + W3R) {
        int t = idx - (8192 + W3R * H2);
        float* b3s = reinterpret_cast<float*>(ws + 17920);
        b3s[t] = (t < 300) ? b3[t] * LOG2E : 0.0f;
    }
}

// consume 16 t-values [T0, T0+16) from own c_buf row; fully static indices.
template<int CH, int HF>
__device__ __forceinline__ void consume3(const float* __restrict__ crow,
                                         const float xr[NI], float v[NI]) {
    constexpr int T0 = CH * 32 + HF * 16;
    if constexpr (T0 < 300) {
        const f32x4* p = reinterpret_cast<const f32x4*>(crow + HF * 16);
        f32x4 cc[4];
        cc[0] = p[0]; cc[1] = p[1]; cc[2] = p[2]; cc[3] = p[3];
        #pragma unroll
        for (int tl = 0; tl < 16; ++tl) {
            if (T0 + tl < 300)
                v[TM.j[T0 + tl]] =
                    fmaf(xr[TM.i[T0 + tl]], cc[tl >> 2][tl & 3], v[TM.j[T0 + tl]]);
        }
    }
}

// one stage-3 chunk: produce 16 own-parity t-cols (all 64 samples), consume
// own row. Entirely wave-private: no __syncthreads.
template<int CH>
__device__ __forceinline__ void chunk3(
    int half, int lr, int lq, int lane,
    const unsigned short* __restrict__ w3b, const float* __restrict__ b3s,
    const float xr[NI], float v[NI],
    float* __restrict__ c_buf, const unsigned short* __restrict__ h2b)
{
    const int my_nt = 2 * CH + half;          // parity == half always
    if (my_nt < NT_TOT) {
        bf16x8 af = *reinterpret_cast<const bf16x8*>(w3b + (my_nt * 16 + lr) * H2 + lq * 8);
        const float4 b4 = *reinterpret_cast<const float4*>(b3s + my_nt * 16 + 4 * lq);
        #pragma unroll
        for (int st = 0; st < 4; ++st) {
            bf16x8 hb = *reinterpret_cast<const bf16x8*>(h2b + (st * 16 + lr) * 40 + lq * 8);
            f32x4 a = {0.f, 0.f, 0.f, 0.f};
            a = __builtin_amdgcn_mfma_f32_16x16x32_bf16(af, hb, a, 0, 0, 0);
            // D: row(4lq+r)=t-in-tile, col(lane&15)=sample-in-st-tile
            f32x4 w;
            w[0] = softplus_g(a[0] + b4.x);
            w[1] = softplus_g(a[1] + b4.y);
            w[2] = softplus_g(a[2] + b4.z);
            w[3] = softplus_g(a[3] + b4.w);
            *reinterpret_cast<f32x4*>(
                c_buf + (st * 16 + lr) * 36 + half * 16 + 4 * lq) = w;
        }
    }
    if (half == 0) consume3<CH, 0>(c_buf + lane * 36, xr, v);
    else           consume3<CH, 1>(c_buf + lane * 36, xr, v);
}

__global__ __launch_bounds__(128, 4) void qnet_fused(
    const float* __restrict__ x,
    const unsigned short* __restrict__ w1b, const float* __restrict__ b1,
    const unsigned short* __restrict__ w2b, const float* __restrict__ b2,
    const unsigned short* __restrict__ w3b, const float* __restrict__ b3s,
    float* __restrict__ y, int B)
{
    // Layout (bytes): h1s [64][40]sh @0..5120 (stages 1-2 only);
    // h2b [64][40]sh @9216..14336 (live through stage 3);
    // c_buf [64][36]f32 @0..9216 overlay (stage 3); vx [64][24]f32 @0 overlay.
    __shared__ __align__(16) unsigned char L[14336];
    unsigned short* h1s = reinterpret_cast<unsigned short*>(L);
    unsigned short* h2b = reinterpret_cast<unsigned short*>(L + 9216);
    float* c_buf = reinterpret_cast<float*>(L);
    float* vx    = reinterpret_cast<float*>(L);

    const int tid  = threadIdx.x;
    const int lane = tid & 63;               // == sample id within block
    const int lr   = lane & 15, lq = lane >> 4;
    const int half = __builtin_amdgcn_readfirstlane(tid >> 6);   // wave id
    const size_t sbase = (size_t)blockIdx.x * SPB;

    // ---- x of own sample, fp32 regs (for quadratic form) ----
    float xr[NI];
    {
        const float4* xp4 = reinterpret_cast<const float4*>(x + (sbase + lane) * NI);
        #pragma unroll
        for (int q = 0; q < NI / 4; ++q) {
            float4 t4 = xp4[q];
            xr[4*q+0] = t4.x; xr[4*q+1] = t4.y; xr[4*q+2] = t4.z; xr[4*q+3] = t4.w;
        }
    }

    // ---- stage-1 x B-frags: K-invariant, held in regs (no LDS staging).
    // lane (lr,lq) needs x[st*16+lr][lq*8..+8]; lq==3 is the K-pad (w1b rows
    // are zero there) -> clamp pointer in-bounds, values irrelevant.
    bf16x8 xf[2];
    #pragma unroll
    for (int u = 0; u < 2; ++u) {
        const int st = 2 * half + u;
        const float* xp = x + (sbase + st * 16 + lr) * NI + (lq == 3 ? 0 : lq * 8);
        float4 x0 = *reinterpret_cast<const float4*>(xp);
        float4 x1 = *reinterpret_cast<const float4*>(xp + 4);
        bf16x8 bf;
        bf[0] = (short)f2bf(x0.x); bf[1] = (short)f2bf(x0.y);
        bf[2] = (short)f2bf(x0.z); bf[3] = (short)f2bf(x0.w);
        bf[4] = (short)f2bf(x1.x); bf[5] = (short)f2bf(x1.y);
        bf[6] = (short)f2bf(x1.z); bf[7] = (short)f2bf(x1.w);
        xf[u] = bf;
    }

    // ---- stages 1+2, K-chunked by 32 h1-rows; wave-private (own 32 samples),
    // stage-2 partials in regs; NO barriers (intra-wave in-order LDS).
    f32x4 acc[2][2];
    #pragma unroll
    for (int u = 0; u < 2; ++u)
        #pragma unroll
        for (int n2 = 0; n2 < 2; ++n2) acc[u][n2] = (f32x4){0.f, 0.f, 0.f, 0.f};

    #pragma unroll
    for (int kk = 0; kk < 4; ++kk) {
        // stage 1: h1 rows [32kk, 32kk+32) for own 32 samples
        #pragma unroll
        for (int n = 0; n < 2; ++n) {
            const int nt1 = 2 * kk + n;
            bf16x8 af = *reinterpret_cast<const bf16x8*>(w1b + (nt1 * 16 + lr) * 32 + lq * 8);
            const float4 bb1 = *reinterpret_cast<const float4*>(b1 + nt1 * 16 + 4 * lq);
            #pragma unroll
            for (int u = 0; u < 2; ++u) {
                const int st = 2 * half + u;
                f32x4 a = {0.f, 0.f, 0.f, 0.f};
                a = __builtin_amdgcn_mfma_f32_16x16x32_bf16(af, xf[u], a, 0, 0, 0);
                unsigned int p0 = pk2(elu_f(a[0] + bb1.x), elu_f(a[1] + bb1.y));
                unsigned int p1 = pk2(elu_f(a[2] + bb1.z), elu_f(a[3] + bb1.w));
                unsigned long long pw = (unsigned long long)p0 | ((unsigned long long)p1 << 32);
                // sample = st*16+lr (own range); local col = n*16 + 4lq + r
                *reinterpret_cast<unsigned long long*>(
                    h1s + (st * 16 + lr) * 40 + n * 16 + 4 * lq) = pw;
            }
        }
        // stage 2: accumulate this K-chunk (reads only own rows)
        #pragma unroll
        for (int u = 0; u < 2; ++u) {
            const int st2 = 2 * half + u;
            bf16x8 hb = *reinterpret_cast<const bf16x8*>(h1s + (st2 * 16 + lr) * 40 + lq * 8);
            #pragma unroll
            for (int n2 = 0; n2 < 2; ++n2) {
                bf16x8 wf = *reinterpret_cast<const bf16x8*>(
                    w2b + (n2 * 16 + lr) * H1 + kk * 32 + lq * 8);
                acc[u][n2] = __builtin_amdgcn_mfma_f32_16x16x32_bf16(wf, hb, acc[u][n2], 0, 0, 0);
            }
        }
    }

    // ---- finish h2: elu + bias, pack bf16 to h2b (own samples) ----
    #pragma unroll
    for (int u = 0; u < 2; ++u) {
        const int st2 = 2 * half + u;
        #pragma unroll
        for (int n2 = 0; n2 < 2; ++n2) {
            const float4 bb2 = *reinterpret_cast<const float4*>(b2 + n2 * 16 + 4 * lq);
            unsigned int p0 = pk2(elu_f(acc[u][n2][0] + bb2.x), elu_f(acc[u][n2][1] + bb2.y));
            unsigned int p1 = pk2(elu_f(acc[u][n2][2] + bb2.z), elu_f(acc[u][n2][3] + bb2.w));
            unsigned long long pw = (unsigned long long)p0 | ((unsigned long long)p1 << 32);
            *reinterpret_cast<unsigned long long*>(
                h2b + (st2 * 16 + lr) * 40 + n2 * 16 + 4 * lq) = pw;
        }
    }
    __syncthreads();   // barrier 1/3: h2b cross-wave; h1s dead -> c_buf region

    // ---- stage 3: 10 chunks, fully wave-private (no barriers) ----
    float v[NI];
    #pragma unroll
    for (int q = 0; q < NI; ++q) v[q] = 0.f;

    chunk3<0>(half, lr, lq, lane, w3b, b3s, xr, v, c_buf, h2b);
    chunk3<1>(half, lr, lq, lane, w3b, b3s, xr, v, c_buf, h2b);
    chunk3<2>(half, lr, lq, lane, w3b, b3s, xr, v, c_buf, h2b);
    chunk3<3>(half, lr, lq, lane, w3b, b3s, xr, v, c_buf, h2b);
    chunk3<4>(half, lr, lq, lane, w3b, b3s, xr, v, c_buf, h2b);
    chunk3<5>(half, lr, lq, lane, w3b, b3s, xr, v, c_buf, h2b);
    chunk3<6>(half, lr, lq, lane, w3b, b3s, xr, v, c_buf, h2b);
    chunk3<7>(half, lr, lq, lane, w3b, b3s, xr, v, c_buf, h2b);
    chunk3<8>(half, lr, lq, lane, w3b, b3s, xr, v, c_buf, h2b);
    chunk3<9>(half, lr, lq, lane, w3b, b3s, xr, v, c_buf, h2b);

    // ---- combine partial v across waves; y = ln2^2 * sum v_j^2 ----
    __syncthreads();   // barrier 2/3: all consumes done before vx overlay
    if (half == 1) {
        f32x4* dst = reinterpret_cast<f32x4*>(vx + lane * 24);
        #pragma unroll
        for (int q = 0; q < 6; ++q) {
            f32x4 t4 = { v[4*q], v[4*q+1], v[4*q+2], v[4*q+3] };
            dst[q] = t4;
        }
    }
    __syncthreads();   // barrier 3/3
    if (half == 0) {
        const f32x4* src = reinterpret_cast<const f32x4*>(vx + lane * 24);
        float acc_y = 0.f;
        #pragma unroll
        for (int q = 0; q < 6; ++q) {
            f32x4 t4 = src[q];
            #pragma unroll
            for (int r = 0; r < 4; ++r) {
                float sv = v[4*q + r] + t4[r];
                acc_y = fmaf(sv, sv, acc_y);
            }
        }
        y[sbase + lane] = LN2SQ * acc_y;
    }
}

extern "C" void kernel_launch(void* const* d_in, const int* in_sizes, int n_in,
                              void* d_out, int out_size, void* d_ws, size_t ws_size,
                              hipStream_t stream) {
    const float* x  = (const float*)d_in[0];
    const float* W1 = (const float*)d_in[1];
    const float* b1 = (const float*)d_in[2];
    const float* W2 = (const float*)d_in[3];
    const float* b2 = (const float*)d_in[4];
    const float* W3 = (const float*)d_in[5];
    const float* b3 = (const float*)d_in[6];
    float* y = (float*)d_out;

    unsigned short* ws = (unsigned short*)d_ws;      // 37056 B used
    const unsigned short* w1b = ws;
    const unsigned short* w2b = ws + 4096;
    const unsigned short* w3b = ws + 8192;
    const float* b3s = reinterpret_cast<const float*>(ws + 17920);

    const int B = in_sizes[0] / NI;   // 131072, divisible by SPB
    const int cvt_elems = 8192 + W3R * H2 + W3R;
    wcvt<<<dim3((cvt_elems + 255) / 256), dim3(256), 0, stream>>>(W1, W2, W3, b3, ws);
    qnet_fused<<<dim3(B / SPB), dim3(128), 0, stream>>>(
        x, w1b, b1, w2b, b2, w3b, b3s, y, B);
}